// Round 9
// baseline (390.163 us; speedup 1.0000x reference)
//
#include <hip/hip_runtime.h>
#include <hip/hip_bf16.h>
#include <math.h>

typedef unsigned short u16;
typedef __bf16 bf16x8 __attribute__((ext_vector_type(8)));
typedef float f32x4 __attribute__((ext_vector_type(4)));

#define NB 32
#define LSEQ 1024
#define DIN 512
#define EDIM 1024
#define SDIM 128
#define NTOK (NB * LSEQ)       // 32768
#define NUV 2176               // 2E + S

#define AS1 __attribute__((address_space(1)))
#define AS3 __attribute__((address_space(3)))

__device__ __forceinline__ u16 f2bf(float f) {
  unsigned u = __builtin_bit_cast(unsigned, f);
  u += 0x7fffu + ((u >> 16) & 1u);
  return (u16)(u >> 16);
}
__device__ __forceinline__ float bf2f(u16 h) {
  unsigned u = ((unsigned)h) << 16;
  return __builtin_bit_cast(float, u);
}
__device__ __forceinline__ float fast_silu(float x) {
  float t = __builtin_amdgcn_exp2f(-1.44269504088896f * x);
  return x * __builtin_amdgcn_rcpf(1.0f + t);
}

// ---------------- small prep kernels ----------------

__global__ __launch_bounds__(256) void k_f32_to_bf16(const float* __restrict__ in,
                                                     u16* __restrict__ out, int n4) {
  int i = blockIdx.x * 256 + threadIdx.x;
  if (i < n4) {
    float4 f = ((const float4*)in)[i];
    ushort4 o;
    o.x = f2bf(f.x); o.y = f2bf(f.y); o.z = f2bf(f.z); o.w = f2bf(f.w);
    ((ushort4*)out)[i] = o;
  }
}

// fused rms-norm + half-shift (reads x once; verified R5)
__global__ __launch_bounds__(256) void k_normshift(const float* __restrict__ x,
                                                   const float* __restrict__ g,
                                                   u16* __restrict__ xn2) {
  int t = blockIdx.x;
  int l = t & (LSEQ - 1);
  float2 v = ((const float2*)(x + (size_t)t * DIN))[threadIdx.x];
  float ss = v.x * v.x + v.y * v.y;
  for (int o = 32; o > 0; o >>= 1) ss += __shfl_down(ss, o, 64);
  __shared__ float p[4];
  if ((threadIdx.x & 63) == 0) p[threadIdx.x >> 6] = ss;
  __syncthreads();
  float s = p[0] + p[1] + p[2] + p[3];
  float norm = sqrtf(s * (1.0f / (float)DIN));
  float inv = g[0] / fmaxf(norm, 1e-5f);
  int d = threadIdx.x * 2;
  ushort2 ob; ob.x = f2bf(v.x * inv); ob.y = f2bf(v.y * inv);
  if (d >= 256) {
    *(ushort2*)(xn2 + (size_t)t * DIN + d) = ob;
  } else {
    if (l < LSEQ - 1) *(ushort2*)(xn2 + (size_t)(t + 1) * DIN + d) = ob;
    if (l == 0) { ushort2 z = {0, 0}; *(ushort2*)(xn2 + (size_t)t * DIN + d) = z; }
  }
}

// RoPE tables in double precision (match numpy)
__global__ __launch_bounds__(256) void k_rope_table(float* __restrict__ sin_t,
                                                    float* __restrict__ cos_t) {
  int idx = blockIdx.x * 256 + threadIdx.x;   // 1024*64
  int l = idx >> 6, j = idx & 63;
  double freq = pow(10000.0, (double)j / 64.0);
  float arg = (float)l * (float)freq;
  double a = (double)arg;
  sin_t[idx] = (float)sin(a);
  cos_t[idx] = (float)cos(a);
}

// base -> q,k with gamma/beta affine + RoPE
__global__ __launch_bounds__(256) void k_qkbuild(const u16* __restrict__ base,
                                                 const float* __restrict__ gamma,
                                                 const float* __restrict__ beta,
                                                 const float* __restrict__ sin_t,
                                                 const float* __restrict__ cos_t,
                                                 u16* __restrict__ q, u16* __restrict__ k) {
  int idx = blockIdx.x * 256 + threadIdx.x;   // NTOK*64
  int t = idx >> 6, j = idx & 63;
  int l = t & (LSEQ - 1);
  float b1 = bf2f(base[(size_t)t * SDIM + j]);
  float b2 = bf2f(base[(size_t)t * SDIM + j + 64]);
  float s = sin_t[l * 64 + j], c = cos_t[l * 64 + j];
  {
    float y1 = b1 * gamma[j] + beta[j];
    float y2 = b2 * gamma[64 + j] + beta[64 + j];
    q[(size_t)t * SDIM + j]      = f2bf(y1 * c - y2 * s);
    q[(size_t)t * SDIM + j + 64] = f2bf(y2 * c + y1 * s);
  }
  {
    float y1 = b1 * gamma[128 + j] + beta[128 + j];
    float y2 = b2 * gamma[192 + j] + beta[192 + j];
    k[(size_t)t * SDIM + j]      = f2bf(y1 * c - y2 * s);
    k[(size_t)t * SDIM + j + 64] = f2bf(y2 * c + y1 * s);
  }
}

// ============ 256x256 8-wave pipelined core, per-slot quadrant schedule ============
// (R7-verified) — used by uv and out.

#define GROW_A(s) (wr * 128 + (s) * 32 + wc * 8)
#define GROW_B(s) (wid * 32 + (s) * 8)

#define STG_PAIR(s, At2, Bt2, dA, dB)                                              \
  do {                                                                             \
    __builtin_amdgcn_global_load_lds(                                              \
        (AS1 unsigned int*)((At2) + (size_t)(GROW_A(s) + srow) * lda + scol),      \
        (AS3 unsigned int*)((dA) + GROW_A(s) * 64), 16, 0, 0);                     \
    __builtin_amdgcn_global_load_lds(                                              \
        (AS1 unsigned int*)((Bt2) + (size_t)(GROW_B(s) + srow) * ldb + scol),      \
        (AS3 unsigned int*)((dB) + GROW_B(s) * 64), 16, 0, 0);                     \
  } while (0)

#define RD_A(dst, cbuf, q)                                                         \
  do {                                                                             \
    _Pragma("unroll") for (int r_ = 0; r_ < 2; ++r_)                               \
    _Pragma("unroll") for (int h_ = 0; h_ < 2; ++h_)                               \
      dst[r_][h_] = *(const bf16x8*)((cbuf) + (wr * 128 + (q) * 32 + r_ * 16 + fr) * 64 + \
                                     (((h_ * 4 + kg) ^ fr7) * 8));                 \
  } while (0)

#define RD_B(cbuf)                                                                 \
  do {                                                                             \
    _Pragma("unroll") for (int n_ = 0; n_ < 4; ++n_)                               \
    _Pragma("unroll") for (int h_ = 0; h_ < 2; ++h_)                               \
      breg[n_][h_] = *(const bf16x8*)((cbuf) + (wc * 64 + n_ * 16 + fr) * 64 +     \
                                      (((h_ * 4 + kg) ^ fr7) * 8));                \
  } while (0)

#define MFMA16(s, areg)                                                            \
  do {                                                                             \
    __builtin_amdgcn_s_setprio(1);                                                 \
    _Pragma("unroll") for (int r_ = 0; r_ < 2; ++r_)                               \
    _Pragma("unroll") for (int n_ = 0; n_ < 4; ++n_)                               \
    _Pragma("unroll") for (int h_ = 0; h_ < 2; ++h_)                               \
      acc[(s) * 2 + r_][n_] = __builtin_amdgcn_mfma_f32_16x16x32_bf16(             \
          areg[r_][h_], breg[n_][h_], acc[(s) * 2 + r_][n_], 0, 0, 0);             \
    __builtin_amdgcn_s_setprio(0);                                                 \
  } while (0)

#define BAR_FENCE()                                                                \
  do { __builtin_amdgcn_s_barrier(); asm volatile("" ::: "memory"); } while (0)

__device__ __forceinline__ void gemm256p_core(const u16* __restrict__ A, int lda,
                                              const u16* __restrict__ B, int ldb,
                                              int K, u16* smem, f32x4 (&acc)[8][4]) {
  const int tid = threadIdx.x;
  const int lane = tid & 63, wid = tid >> 6;
  const int wr = wid >> 2, wc = wid & 3;
  const int fr = lane & 15, kg = lane >> 4, fr7 = fr & 7;
  const int srow = lane >> 3;
  const int scol = ((lane & 7) ^ srow) * 8;
  u16* cA = smem;
  u16* cB = smem + 16384;
  u16* nA = smem + 32768;
  u16* nB = smem + 49152;
  const int nt = K >> 6;

#pragma unroll
  for (int s = 0; s < 4; ++s) STG_PAIR(s, A, B, cA, cB);
#pragma unroll
  for (int s = 0; s < 4; ++s) STG_PAIR(s, A + 64, B + 64, nA, nB);
  asm volatile("s_waitcnt vmcnt(8)" ::: "memory");
  BAR_FENCE();

  bf16x8 breg[4][2], ac[2][2], an[2][2];
  RD_B(cB);
  RD_A(ac, cA, 0);

  for (int t = 0; t < nt; ++t) {
    const bool st = (t + 2) < nt;
    const u16* At2 = A + (size_t)(t + 2) * 64;
    const u16* Bt2 = B + (size_t)(t + 2) * 64;
    MFMA16(0, ac);
    RD_A(an, cA, 1);
    BAR_FENCE();
    if (st) STG_PAIR(0, At2, Bt2, cA, cB);
    MFMA16(1, an);
    RD_A(ac, cA, 2);
    BAR_FENCE();
    if (st) STG_PAIR(1, At2, Bt2, cA, cB);
    MFMA16(2, ac);
    RD_A(an, cA, 3);
    BAR_FENCE();
    if (st) STG_PAIR(2, At2, Bt2, cA, cB);
    MFMA16(3, an);
    if (st) asm volatile("s_waitcnt vmcnt(6)" ::: "memory");
    else    asm volatile("s_waitcnt vmcnt(0)" ::: "memory");
    BAR_FENCE();
    if (st) STG_PAIR(3, At2, Bt2, cA, cB);
    { u16* tp = cA; cA = nA; nA = tp; tp = cB; cB = nB; nB = tp; }
    if (t + 1 < nt) { RD_B(cB); RD_A(ac, cA, 0); }
  }
}

// GEMM1: uv = silu(xn2 @ uv_w^T). Grid 1152 = 8 XCDs x 16 M-tiles x 9 N-tiles.
__global__ __launch_bounds__(512, 2) void k_gemm_uv(const u16* __restrict__ xn2,
                                                    const u16* __restrict__ wbf,
                                                    u16* __restrict__ u, u16* __restrict__ vt,
                                                    u16* __restrict__ base) {
  __shared__ __align__(16) u16 smem[65536];
  f32x4 acc[8][4] = {};
  int bid = blockIdx.x;
  int xcd = bid & 7;
  int off = bid >> 3;                 // 0..143
  int m0 = (xcd * 16 + off / 9) * 256;
  int n0 = (off % 9) * 256;
  gemm256p_core(xn2 + (size_t)m0 * DIN, DIN, wbf + (size_t)n0 * DIN, DIN, DIN, smem, acc);
  int lane = threadIdx.x & 63, wid = threadIdx.x >> 6;
  int wr = wid >> 2, wc = wid & 3;
  int cb = n0 + wc * 64 + (lane & 15);
  int rb = m0 + wr * 128 + (lane >> 4) * 4;
  if (n0 < EDIM) {                       // u columns
#pragma unroll
    for (int mm = 0; mm < 8; ++mm)
#pragma unroll
      for (int n = 0; n < 4; ++n) {
        int c = cb + n * 16;
#pragma unroll
        for (int j = 0; j < 4; ++j) {
          int r = rb + mm * 16 + j;
          u[(size_t)r * EDIM + c] = f2bf(fast_silu(acc[mm][n][j]));
        }
      }
  } else if (n0 < 2 * EDIM) {            // v columns -> transposed store
    int b = m0 >> 10;
    u16* vtb = vt + (size_t)b * (EDIM * LSEQ);
#pragma unroll
    for (int mm = 0; mm < 8; ++mm) {
      int l0 = (rb + mm * 16) & (LSEQ - 1);
#pragma unroll
      for (int n = 0; n < 4; ++n) {
        int e = cb + n * 16 - EDIM;
        ushort4 o;
        o.x = f2bf(fast_silu(acc[mm][n][0]));
        o.y = f2bf(fast_silu(acc[mm][n][1]));
        o.z = f2bf(fast_silu(acc[mm][n][2]));
        o.w = f2bf(fast_silu(acc[mm][n][3]));
        *(ushort4*)(vtb + (size_t)e * LSEQ + l0) = o;
      }
    }
  } else if (wc < 2) {                   // base columns (valid half-tile)
#pragma unroll
    for (int mm = 0; mm < 8; ++mm)
#pragma unroll
      for (int n = 0; n < 4; ++n) {
        int c = cb + n * 16 - 2 * EDIM;
#pragma unroll
        for (int j = 0; j < 4; ++j) {
          int r = rb + mm * 16 + j;
          base[(size_t)r * SDIM + c] = f2bf(fast_silu(acc[mm][n][j]));
        }
      }
  }
}

// ============ Fused attention: u_io <- u_io .* ( relu((qK^T+w)/sqrtS)^2 @ V ) ============
// Tile 128m x 128e, 16 kv-chunks of 64. Single k-buffer (restaged under PV),
// double v-buffer, counted vmcnt(2). LDS 68.5KB -> 2 blocks/CU.
// sS swizzle mask (row>>1)&7: rows {j,j+4,j+8,j+12} get 4 distinct masks -> write
// conflicts minimal (2 lanes/bank-word, same-dword halves); reads stay spread.
__global__ __launch_bounds__(512, 4) void k_attn(const u16* __restrict__ qg_,
                                                 const u16* __restrict__ kg_,
                                                 const u16* __restrict__ vtg,
                                                 const float* __restrict__ w,
                                                 u16* u_io) {
  __shared__ __align__(16) u16 smem[35072];   // 70144 B
  u16* kb = smem;                                        // 16KB: [64 l][128 d]
  u16* v0 = smem + 8192;     u16* v1 = smem + 16384;     // 16KB each: [128 e][64 l]
  u16* sS = smem + 24576;                                // 16KB: [128 m][64 l]
  float* wwin = (float*)(smem + 32768);                  // 1152 f32

  const int tid = threadIdx.x;
  const int lane = tid & 63, wid = tid >> 6;
  const int fr = lane & 15, kg = lane >> 4, fr7 = fr & 7;
  int bid = blockIdx.x;
  int xcd = bid & 7;
  int idx = bid >> 3;                  // 0..255
  int b = xcd * 4 + (idx >> 6);        // batch
  int t6 = idx & 63;
  int m0 = (t6 >> 3) * 128;            // 0..896
  int e0 = (t6 & 7) * 128;
  const u16* qp = qg_ + (size_t)(b * LSEQ) * SDIM;
  const u16* kp = kg_ + (size_t)(b * LSEQ) * SDIM;
  const u16* vp = vtg + (size_t)b * LSEQ * EDIM + (size_t)e0 * LSEQ;

  // q fragments in registers: wave wid owns m-rows [wid*16, wid*16+16)
  bf16x8 qreg[4];
#pragma unroll
  for (int kf = 0; kf < 4; ++kf)
    qreg[kf] = *(const bf16x8*)(qp + (size_t)(m0 + wid * 16 + fr) * SDIM + kf * 32 + kg * 8);

  // w window: wwin[i] = w[896 - m0 + i], i in [0,1152)
  if (tid < 288)
    __builtin_amdgcn_global_load_lds((AS1 unsigned int*)(w + (896 - m0) + tid * 4),
                                     (AS3 unsigned int*)(wwin + tid * 4), 16, 0, 0);

  // stage k chunk (2 loads/thread): [64 l][128 d], 16 slots/row, low-3-bit XOR
  auto stage_k = [&](const u16* src_base) {
#pragma unroll
    for (int j2 = 0; j2 < 2; ++j2) {
      int ix = tid + j2 * 512;
      int row = ix >> 4, slot = ix & 15;
      int sslot = (slot & 8) | ((slot & 7) ^ (row & 7));
      __builtin_amdgcn_global_load_lds((AS1 unsigned int*)(src_base + (size_t)row * SDIM + sslot * 8),
                                       (AS3 unsigned int*)(kb + ix * 8), 16, 0, 0);
    }
  };
  // stage vt chunk (2 loads/thread): [128 e][64 l], 8 slots/row
  auto stage_vt = [&](const u16* src_base, u16* dst) {
#pragma unroll
    for (int j2 = 0; j2 < 2; ++j2) {
      int ix = tid + j2 * 512;
      int row = ix >> 3, slot = (ix & 7) ^ (row & 7);
      __builtin_amdgcn_global_load_lds((AS1 unsigned int*)(src_base + (size_t)row * LSEQ + slot * 8),
                                       (AS3 unsigned int*)(dst + ix * 8), 16, 0, 0);
    }
  };

  stage_k(kp);
  stage_vt(vp, v0);
  stage_vt(vp + 64, v1);
  asm volatile("s_waitcnt vmcnt(2)" ::: "memory");   // qreg+wwin+k0+v0 landed, v1 in flight
  __builtin_amdgcn_sched_barrier(0);
  BAR_FENCE();

  const int wr = wid >> 2, wc = wid & 3;
  f32x4 acc[4][2] = {};
  const float inv_sqrt_s = 0.08838834764831845f;

  for (int t = 0; t < 16; ++t) {
    u16* vc = (t & 1) ? v1 : v0;
    int l0 = t * 64;
    // ---- S phase: S[128m][64l] = q . k^T over K=128 ----
    f32x4 sacc[4] = {};
#pragma unroll
    for (int n = 0; n < 4; ++n)
#pragma unroll
      for (int kf = 0; kf < 4; ++kf) {
        int sl = kf * 4 + kg;
        int sw = (sl & 8) | ((sl & 7) ^ fr7);
        bf16x8 kfr = *(const bf16x8*)(kb + (n * 16 + fr) * 128 + sw * 8);
        sacc[n] = __builtin_amdgcn_mfma_f32_16x16x32_bf16(qreg[kf], kfr, sacc[n], 0, 0, 0);
      }
    // epilogue: bias + relu^2, write S to LDS ([m][l], mask (row>>1)&7)
    {
      int mbase = wid * 16 + kg * 4;
#pragma unroll
      for (int n = 0; n < 4; ++n) {
        int lloc = n * 16 + fr;
#pragma unroll
        for (int j = 0; j < 4; ++j) {
          int row = mbase + j;
          float val = (sacc[n][j] + wwin[l0 + lloc + 127 - row]) * inv_sqrt_s;
          val = fmaxf(val, 0.0f);
          int sw = (lloc >> 3) ^ ((row >> 1) & 7);
          sS[row * 64 + sw * 8 + (lloc & 7)] = f2bf(val * val);
        }
      }
    }
    asm volatile("s_waitcnt lgkmcnt(0)" ::: "memory");
    __builtin_amdgcn_sched_barrier(0);
    BAR_FENCE();                                   // S visible; kb free
    if (t + 1 < 16) stage_k(kp + (size_t)(l0 + 64) * SDIM);
    // ---- PV phase: acc += S(128x64) @ vt-chunk ----
#pragma unroll
    for (int kh = 0; kh < 2; ++kh) {
      bf16x8 afr[4], bfr[2];
#pragma unroll
      for (int i = 0; i < 4; ++i) {
        int row = wr * 64 + i * 16 + fr;
        int sw = (kh * 4 + kg) ^ ((row >> 1) & 7);
        afr[i] = *(const bf16x8*)(sS + row * 64 + sw * 8);
      }
#pragma unroll
      for (int n = 0; n < 2; ++n) {
        int row = wc * 32 + n * 16 + fr;
        int sw = (kh * 4 + kg) ^ (fr & 7);
        bfr[n] = *(const bf16x8*)(vc + row * 64 + sw * 8);
      }
      __builtin_amdgcn_s_setprio(1);
#pragma unroll
      for (int i = 0; i < 4; ++i)
#pragma unroll
        for (int n = 0; n < 2; ++n)
          acc[i][n] = __builtin_amdgcn_mfma_f32_16x16x32_bf16(afr[i], bfr[n], acc[i][n], 0, 0, 0);
      __builtin_amdgcn_s_setprio(0);
    }
    BAR_FENCE();                                   // vc + sS reads done
    if (t + 2 < 16) stage_vt(vp + (l0 + 128), vc);
    if (t + 2 < 16) asm volatile("s_waitcnt vmcnt(2)" ::: "memory");  // k(t+1),v(t+1) landed
    else            asm volatile("s_waitcnt vmcnt(0)" ::: "memory");
    __builtin_amdgcn_sched_barrier(0);
    BAR_FENCE();                                   // chunk t+1 ready
  }

  // gate with u (in place)
  int cb = e0 + wc * 32 + fr;
  int rb = m0 + wr * 64 + kg * 4;
#pragma unroll
  for (int i = 0; i < 4; ++i)
#pragma unroll
    for (int n = 0; n < 2; ++n) {
      int c = cb + n * 16;
#pragma unroll
      for (int j = 0; j < 4; ++j) {
        int r = rb + i * 16 + j;
        size_t ix = (size_t)(b * LSEQ + r) * EDIM + c;
        u_io[ix] = f2bf(acc[i][n][j] * bf2f(u_io[ix]));
      }
    }
}

// GEMM4: out = x*res_scale + (attn @ o_w^T)*layer_scale.  256^2 pipelined core.
__global__ __launch_bounds__(512, 2) void k_gemm_out(const u16* __restrict__ attn,
                                                     const u16* __restrict__ owbf,
                                                     const float* __restrict__ x,
                                                     const float* __restrict__ res_scale,
                                                     const float* __restrict__ layer_scale,
                                                     float* __restrict__ out) {
  __shared__ __align__(16) u16 smem[65536];
  f32x4 acc[8][4] = {};
  int bid = blockIdx.x;
  int xcd = bid & 7;
  int off = bid >> 3;                 // 0..31
  int m0 = (xcd * 16 + (off >> 1)) * 256;
  int n0 = (off & 1) * 256;
  gemm256p_core(attn + (size_t)m0 * EDIM, EDIM, owbf + (size_t)n0 * EDIM, EDIM,
                EDIM, smem, acc);
  int lane = threadIdx.x & 63, wid = threadIdx.x >> 6;
  int wr = wid >> 2, wc = wid & 3;
  int cb = n0 + wc * 64 + (lane & 15);
  int rb = m0 + wr * 128 + (lane >> 4) * 4;
#pragma unroll
  for (int mm = 0; mm < 8; ++mm)
#pragma unroll
    for (int n = 0; n < 4; ++n) {
      int c = cb + n * 16;
#pragma unroll
      for (int j = 0; j < 4; ++j) {
        int r = rb + mm * 16 + j;
        out[(size_t)r * DIN + c] =
            x[(size_t)r * DIN + c] * res_scale[c] + acc[mm][n][j] * layer_scale[c];
      }
    }
}

// ---------------- launch ----------------

extern "C" void kernel_launch(void* const* d_in, const int* in_sizes, int n_in,
                              void* d_out, int out_size, void* d_ws, size_t ws_size,
                              hipStream_t stream) {
  const float* x          = (const float*)d_in[0];
  const float* uv_w       = (const float*)d_in[1];
  const float* o_w        = (const float*)d_in[2];
  const float* gamma      = (const float*)d_in[3];
  const float* beta       = (const float*)d_in[4];
  const float* w          = (const float*)d_in[5];
  const float* g          = (const float*)d_in[6];
  const float* res_scale  = (const float*)d_in[7];
  const float* layer_scale= (const float*)d_in[8];
  float* out = (float*)d_out;

  char* ws = (char*)d_ws;
  // workspace layout (bytes), peak ~189 MB (< proven-good 197):
  u16* xn2    = (u16*)(ws + 0);            // 32 MB, dead after gemm_uv
  u16* q      = (u16*)(ws + 0);            // 8 MB (aliases dead xn2)
  u16* k      = (u16*)(ws + 8388608);      // 8 MB (aliases dead xn2)
  u16* base   = (u16*)(ws + 33554432);     // 8 MB, live gemm_uv -> qkbuild
  u16* u_io   = (u16*)(ws + 50331648);     // 64 MB: u, gated in place -> attn
  u16* vt     = (u16*)(ws + 117440512);    // 64 MB: v^T per batch
  u16* uvw_bf = (u16*)(ws + 184549376);    // 2.125 MB (+0.125 MB pad-read slack)
  u16* ow_bf  = (u16*)(ws + 186908672);    // 1 MB
  float* sin_t = (float*)(ws + 187957248); // 256 KB
  float* cos_t = (float*)(ws + 188219392); // 256 KB

  // prep
  k_f32_to_bf16<<<dim3((NUV * DIN / 4 + 255) / 256), 256, 0, stream>>>(uv_w, uvw_bf, NUV * DIN / 4);
  k_f32_to_bf16<<<dim3((DIN * EDIM / 4 + 255) / 256), 256, 0, stream>>>(o_w, ow_bf, DIN * EDIM / 4);
  k_rope_table<<<dim3(LSEQ * 64 / 256), 256, 0, stream>>>(sin_t, cos_t);
  k_normshift<<<dim3(NTOK), 256, 0, stream>>>(x, g, xn2);

  // uv projection + silu (256^2 per-slot-staged pipelined core)
  k_gemm_uv<<<dim3(1152), 512, 0, stream>>>(xn2, uvw_bf, u_io, vt, base);

  // q,k build (writes into dead xn2 region)
  k_qkbuild<<<dim3(NTOK * 64 / 256), 256, 0, stream>>>(base, gamma, beta, sin_t, cos_t, q, k);

  // fused attention: scores never touch memory. Grid 2048 = 8 XCDs x 4 batches x 64 tiles.
  k_attn<<<dim3(2048), 512, 0, stream>>>(q, k, vt, w, u_io);

  // final projection + residual (256^2 pipelined core)
  k_gemm_out<<<dim3(256), 512, 0, stream>>>(u_io, ow_bf, x, res_scale, layer_scale, out);
}

// Round 10
// 311.615 us; speedup vs baseline: 1.2521x; 1.2521x over previous
//
#include <hip/hip_runtime.h>
#include <hip/hip_bf16.h>
#include <math.h>

typedef unsigned short u16;
typedef __bf16 bf16x8 __attribute__((ext_vector_type(8)));
typedef float f32x4 __attribute__((ext_vector_type(4)));

#define NB 32
#define LSEQ 1024
#define DIN 512
#define EDIM 1024
#define SDIM 128
#define NTOK (NB * LSEQ)       // 32768
#define NUV 2176               // 2E + S
#define CHUNK 16               // batches per qk/pv chunk

#define AS1 __attribute__((address_space(1)))
#define AS3 __attribute__((address_space(3)))

__device__ __forceinline__ u16 f2bf(float f) {
  unsigned u = __builtin_bit_cast(unsigned, f);
  u += 0x7fffu + ((u >> 16) & 1u);
  return (u16)(u >> 16);
}
__device__ __forceinline__ float bf2f(u16 h) {
  unsigned u = ((unsigned)h) << 16;
  return __builtin_bit_cast(float, u);
}
__device__ __forceinline__ float fast_silu(float x) {
  float t = __builtin_amdgcn_exp2f(-1.44269504088896f * x);
  return x * __builtin_amdgcn_rcpf(1.0f + t);
}

// ---------------- small prep kernels ----------------

__global__ __launch_bounds__(256) void k_f32_to_bf16(const float* __restrict__ in,
                                                     u16* __restrict__ out, int n4) {
  int i = blockIdx.x * 256 + threadIdx.x;
  if (i < n4) {
    float4 f = ((const float4*)in)[i];
    ushort4 o;
    o.x = f2bf(f.x); o.y = f2bf(f.y); o.z = f2bf(f.z); o.w = f2bf(f.w);
    ((ushort4*)out)[i] = o;
  }
}

// fused rms-norm + half-shift (reads x once; verified R5)
__global__ __launch_bounds__(256) void k_normshift(const float* __restrict__ x,
                                                   const float* __restrict__ g,
                                                   u16* __restrict__ xn2) {
  int t = blockIdx.x;
  int l = t & (LSEQ - 1);
  float2 v = ((const float2*)(x + (size_t)t * DIN))[threadIdx.x];
  float ss = v.x * v.x + v.y * v.y;
  for (int o = 32; o > 0; o >>= 1) ss += __shfl_down(ss, o, 64);
  __shared__ float p[4];
  if ((threadIdx.x & 63) == 0) p[threadIdx.x >> 6] = ss;
  __syncthreads();
  float s = p[0] + p[1] + p[2] + p[3];
  float norm = sqrtf(s * (1.0f / (float)DIN));
  float inv = g[0] / fmaxf(norm, 1e-5f);
  int d = threadIdx.x * 2;
  ushort2 ob; ob.x = f2bf(v.x * inv); ob.y = f2bf(v.y * inv);
  if (d >= 256) {
    *(ushort2*)(xn2 + (size_t)t * DIN + d) = ob;
  } else {
    if (l < LSEQ - 1) *(ushort2*)(xn2 + (size_t)(t + 1) * DIN + d) = ob;
    if (l == 0) { ushort2 z = {0, 0}; *(ushort2*)(xn2 + (size_t)t * DIN + d) = z; }
  }
}

// RoPE tables in double precision (match numpy)
__global__ __launch_bounds__(256) void k_rope_table(float* __restrict__ sin_t,
                                                    float* __restrict__ cos_t) {
  int idx = blockIdx.x * 256 + threadIdx.x;   // 1024*64
  int l = idx >> 6, j = idx & 63;
  double freq = pow(10000.0, (double)j / 64.0);
  float arg = (float)l * (float)freq;
  double a = (double)arg;
  sin_t[idx] = (float)sin(a);
  cos_t[idx] = (float)cos(a);
}

// base -> q,k with gamma/beta affine + RoPE
__global__ __launch_bounds__(256) void k_qkbuild(const u16* __restrict__ base,
                                                 const float* __restrict__ gamma,
                                                 const float* __restrict__ beta,
                                                 const float* __restrict__ sin_t,
                                                 const float* __restrict__ cos_t,
                                                 u16* __restrict__ q, u16* __restrict__ k) {
  int idx = blockIdx.x * 256 + threadIdx.x;   // NTOK*64
  int t = idx >> 6, j = idx & 63;
  int l = t & (LSEQ - 1);
  float b1 = bf2f(base[(size_t)t * SDIM + j]);
  float b2 = bf2f(base[(size_t)t * SDIM + j + 64]);
  float s = sin_t[l * 64 + j], c = cos_t[l * 64 + j];
  {
    float y1 = b1 * gamma[j] + beta[j];
    float y2 = b2 * gamma[64 + j] + beta[64 + j];
    q[(size_t)t * SDIM + j]      = f2bf(y1 * c - y2 * s);
    q[(size_t)t * SDIM + j + 64] = f2bf(y2 * c + y1 * s);
  }
  {
    float y1 = b1 * gamma[128 + j] + beta[128 + j];
    float y2 = b2 * gamma[192 + j] + beta[192 + j];
    k[(size_t)t * SDIM + j]      = f2bf(y1 * c - y2 * s);
    k[(size_t)t * SDIM + j + 64] = f2bf(y2 * c + y1 * s);
  }
}

// ============ 256x256 8-wave pipelined core, per-slot quadrant schedule ============
// (R7-verified) — used by uv, qk, pv, out.

#define GROW_A(s) (wr * 128 + (s) * 32 + wc * 8)
#define GROW_B(s) (wid * 32 + (s) * 8)

#define STG_PAIR(s, At2, Bt2, dA, dB)                                              \
  do {                                                                             \
    __builtin_amdgcn_global_load_lds(                                              \
        (AS1 unsigned int*)((At2) + (size_t)(GROW_A(s) + srow) * lda + scol),      \
        (AS3 unsigned int*)((dA) + GROW_A(s) * 64), 16, 0, 0);                     \
    __builtin_amdgcn_global_load_lds(                                              \
        (AS1 unsigned int*)((Bt2) + (size_t)(GROW_B(s) + srow) * ldb + scol),      \
        (AS3 unsigned int*)((dB) + GROW_B(s) * 64), 16, 0, 0);                     \
  } while (0)

#define RD_A(dst, cbuf, q)                                                         \
  do {                                                                             \
    _Pragma("unroll") for (int r_ = 0; r_ < 2; ++r_)                               \
    _Pragma("unroll") for (int h_ = 0; h_ < 2; ++h_)                               \
      dst[r_][h_] = *(const bf16x8*)((cbuf) + (wr * 128 + (q) * 32 + r_ * 16 + fr) * 64 + \
                                     (((h_ * 4 + kg) ^ fr7) * 8));                 \
  } while (0)

#define RD_B(cbuf)                                                                 \
  do {                                                                             \
    _Pragma("unroll") for (int n_ = 0; n_ < 4; ++n_)                               \
    _Pragma("unroll") for (int h_ = 0; h_ < 2; ++h_)                               \
      breg[n_][h_] = *(const bf16x8*)((cbuf) + (wc * 64 + n_ * 16 + fr) * 64 +     \
                                      (((h_ * 4 + kg) ^ fr7) * 8));                \
  } while (0)

#define MFMA16(s, areg)                                                            \
  do {                                                                             \
    __builtin_amdgcn_s_setprio(1);                                                 \
    _Pragma("unroll") for (int r_ = 0; r_ < 2; ++r_)                               \
    _Pragma("unroll") for (int n_ = 0; n_ < 4; ++n_)                               \
    _Pragma("unroll") for (int h_ = 0; h_ < 2; ++h_)                               \
      acc[(s) * 2 + r_][n_] = __builtin_amdgcn_mfma_f32_16x16x32_bf16(             \
          areg[r_][h_], breg[n_][h_], acc[(s) * 2 + r_][n_], 0, 0, 0);             \
    __builtin_amdgcn_s_setprio(0);                                                 \
  } while (0)

#define BAR_FENCE()                                                                \
  do { __builtin_amdgcn_s_barrier(); asm volatile("" ::: "memory"); } while (0)

__device__ __forceinline__ void gemm256p_core(const u16* __restrict__ A, int lda,
                                              const u16* __restrict__ B, int ldb,
                                              int K, u16* smem, f32x4 (&acc)[8][4]) {
  const int tid = threadIdx.x;
  const int lane = tid & 63, wid = tid >> 6;
  const int wr = wid >> 2, wc = wid & 3;
  const int fr = lane & 15, kg = lane >> 4, fr7 = fr & 7;
  const int srow = lane >> 3;
  const int scol = ((lane & 7) ^ srow) * 8;
  u16* cA = smem;
  u16* cB = smem + 16384;
  u16* nA = smem + 32768;
  u16* nB = smem + 49152;
  const int nt = K >> 6;

#pragma unroll
  for (int s = 0; s < 4; ++s) STG_PAIR(s, A, B, cA, cB);
#pragma unroll
  for (int s = 0; s < 4; ++s) STG_PAIR(s, A + 64, B + 64, nA, nB);
  asm volatile("s_waitcnt vmcnt(8)" ::: "memory");
  BAR_FENCE();

  bf16x8 breg[4][2], ac[2][2], an[2][2];
  RD_B(cB);
  RD_A(ac, cA, 0);

  for (int t = 0; t < nt; ++t) {
    const bool st = (t + 2) < nt;
    const u16* At2 = A + (size_t)(t + 2) * 64;
    const u16* Bt2 = B + (size_t)(t + 2) * 64;
    MFMA16(0, ac);
    RD_A(an, cA, 1);
    BAR_FENCE();
    if (st) STG_PAIR(0, At2, Bt2, cA, cB);
    MFMA16(1, an);
    RD_A(ac, cA, 2);
    BAR_FENCE();
    if (st) STG_PAIR(1, At2, Bt2, cA, cB);
    MFMA16(2, ac);
    RD_A(an, cA, 3);
    BAR_FENCE();
    if (st) STG_PAIR(2, At2, Bt2, cA, cB);
    MFMA16(3, an);
    if (st) asm volatile("s_waitcnt vmcnt(6)" ::: "memory");
    else    asm volatile("s_waitcnt vmcnt(0)" ::: "memory");
    BAR_FENCE();
    if (st) STG_PAIR(3, At2, Bt2, cA, cB);
    { u16* tp = cA; cA = nA; nA = tp; tp = cB; cB = nB; nB = tp; }
    if (t + 1 < nt) { RD_B(cB); RD_A(ac, cA, 0); }
  }
}

// GEMM1: uv = silu(xn2 @ uv_w^T). Grid 1152 = 8 XCDs x 16 M-tiles x 9 N-tiles.
__global__ __launch_bounds__(512, 2) void k_gemm_uv(const u16* __restrict__ xn2,
                                                    const u16* __restrict__ wbf,
                                                    u16* __restrict__ u, u16* __restrict__ vt,
                                                    u16* __restrict__ base) {
  __shared__ __align__(16) u16 smem[65536];
  f32x4 acc[8][4] = {};
  int bid = blockIdx.x;
  int xcd = bid & 7;
  int off = bid >> 3;                 // 0..143
  int m0 = (xcd * 16 + off / 9) * 256;
  int n0 = (off % 9) * 256;
  gemm256p_core(xn2 + (size_t)m0 * DIN, DIN, wbf + (size_t)n0 * DIN, DIN, DIN, smem, acc);
  int lane = threadIdx.x & 63, wid = threadIdx.x >> 6;
  int wr = wid >> 2, wc = wid & 3;
  int cb = n0 + wc * 64 + (lane & 15);
  int rb = m0 + wr * 128 + (lane >> 4) * 4;
  if (n0 < EDIM) {                       // u columns
#pragma unroll
    for (int mm = 0; mm < 8; ++mm)
#pragma unroll
      for (int n = 0; n < 4; ++n) {
        int c = cb + n * 16;
#pragma unroll
        for (int j = 0; j < 4; ++j) {
          int r = rb + mm * 16 + j;
          u[(size_t)r * EDIM + c] = f2bf(fast_silu(acc[mm][n][j]));
        }
      }
  } else if (n0 < 2 * EDIM) {            // v columns -> transposed store
    int b = m0 >> 10;
    u16* vtb = vt + (size_t)b * (EDIM * LSEQ);
#pragma unroll
    for (int mm = 0; mm < 8; ++mm) {
      int l0 = (rb + mm * 16) & (LSEQ - 1);
#pragma unroll
      for (int n = 0; n < 4; ++n) {
        int e = cb + n * 16 - EDIM;
        ushort4 o;
        o.x = f2bf(fast_silu(acc[mm][n][0]));
        o.y = f2bf(fast_silu(acc[mm][n][1]));
        o.z = f2bf(fast_silu(acc[mm][n][2]));
        o.w = f2bf(fast_silu(acc[mm][n][3]));
        *(ushort4*)(vtb + (size_t)e * LSEQ + l0) = o;
      }
    }
  } else if (wc < 2) {                   // base columns (valid half-tile)
#pragma unroll
    for (int mm = 0; mm < 8; ++mm)
#pragma unroll
      for (int n = 0; n < 4; ++n) {
        int c = cb + n * 16 - 2 * EDIM;
#pragma unroll
        for (int j = 0; j < 4; ++j) {
          int r = rb + mm * 16 + j;
          base[(size_t)r * SDIM + c] = f2bf(fast_silu(acc[mm][n][j]));
        }
      }
  }
}

// GEMM2: scores = relu((q k^T + w)/sqrt(S))^2.  256^2 pipelined core (nt=2:
// both K-tiles staged in prologue; tile-1 loads land under tile-0 compute).
// Grid 256 = 8 XCDs x 2 batches x 16 tiles (16 batches per launch).
__global__ __launch_bounds__(512, 2) void k_gemm_qk(const u16* __restrict__ q,
                                                    const u16* __restrict__ k,
                                                    const float* __restrict__ w,
                                                    u16* __restrict__ scores) {
  __shared__ __align__(16) u16 smem[65536];
  f32x4 acc[8][4] = {};
  int bid = blockIdx.x;
  int xcd = bid & 7;
  int off = bid >> 3;                    // 0..31
  int b = xcd * 2 + (off >> 4);          // chunk-local batch
  int t = off & 15;
  int m0 = (t >> 2) * 256, n0 = (t & 3) * 256;
  gemm256p_core(q + (size_t)(b * LSEQ + m0) * SDIM, SDIM,
                k + (size_t)(b * LSEQ + n0) * SDIM, SDIM,
                SDIM, smem, acc);
  int lane = threadIdx.x & 63, wid = threadIdx.x >> 6;
  int wr = wid >> 2, wc = wid & 3;
  int cb = n0 + wc * 64 + (lane & 15);
  int rb = m0 + wr * 128 + (lane >> 4) * 4;
  const float inv_sqrt_s = 0.08838834764831845f;
  u16* sc_b = scores + (size_t)b * LSEQ * LSEQ;
#pragma unroll
  for (int mm = 0; mm < 8; ++mm)
#pragma unroll
    for (int n = 0; n < 4; ++n) {
      int c = cb + n * 16;
#pragma unroll
      for (int j = 0; j < 4; ++j) {
        int r = rb + mm * 16 + j;
        float val = (acc[mm][n][j] + w[c - r + (LSEQ - 1)]) * inv_sqrt_s;
        val = fmaxf(val, 0.0f);
        sc_b[(size_t)r * LSEQ + c] = f2bf(val * val);
      }
    }
}

// GEMM3: u_io <- u_io .* (scores @ v).  256^2 pipelined core.
// Grid 256 = 8 XCDs x 2 batches x 16 tiles (16 batches per launch).
__global__ __launch_bounds__(512, 2) void k_gemm_pv(const u16* __restrict__ scores,
                                                    const u16* __restrict__ vt,
                                                    u16* u_io) {
  __shared__ __align__(16) u16 smem[65536];
  f32x4 acc[8][4] = {};
  int bid = blockIdx.x;
  int xcd = bid & 7;
  int off = bid >> 3;                    // 0..31
  int b = xcd * 2 + (off >> 4);          // chunk-local batch
  int t = off & 15;
  int m0 = (t >> 2) * 256, n0 = (t & 3) * 256;
  gemm256p_core(scores + (size_t)b * LSEQ * LSEQ + (size_t)m0 * LSEQ, LSEQ,
                vt + (size_t)b * LSEQ * EDIM + (size_t)n0 * LSEQ, LSEQ,
                LSEQ, smem, acc);
  int lane = threadIdx.x & 63, wid = threadIdx.x >> 6;
  int wr = wid >> 2, wc = wid & 3;
  int cb = n0 + wc * 64 + (lane & 15);
  int rb = m0 + wr * 128 + (lane >> 4) * 4;
#pragma unroll
  for (int mm = 0; mm < 8; ++mm)
#pragma unroll
    for (int n = 0; n < 4; ++n) {
      int c = cb + n * 16;
#pragma unroll
      for (int j = 0; j < 4; ++j) {
        int r = rb + mm * 16 + j;
        size_t idx = (size_t)(b * LSEQ + r) * EDIM + c;
        u_io[idx] = f2bf(acc[mm][n][j] * bf2f(u_io[idx]));
      }
    }
}

// GEMM4: out = x*res_scale + (attn @ o_w^T)*layer_scale.  256^2 pipelined core.
// Grid 256 = 8 XCDs x 16 M-tiles x 2 N-tiles.
__global__ __launch_bounds__(512, 2) void k_gemm_out(const u16* __restrict__ attn,
                                                     const u16* __restrict__ owbf,
                                                     const float* __restrict__ x,
                                                     const float* __restrict__ res_scale,
                                                     const float* __restrict__ layer_scale,
                                                     float* __restrict__ out) {
  __shared__ __align__(16) u16 smem[65536];
  f32x4 acc[8][4] = {};
  int bid = blockIdx.x;
  int xcd = bid & 7;
  int off = bid >> 3;                 // 0..31
  int m0 = (xcd * 16 + (off >> 1)) * 256;
  int n0 = (off & 1) * 256;
  gemm256p_core(attn + (size_t)m0 * EDIM, EDIM, owbf + (size_t)n0 * EDIM, EDIM,
                EDIM, smem, acc);
  int lane = threadIdx.x & 63, wid = threadIdx.x >> 6;
  int wr = wid >> 2, wc = wid & 3;
  int cb = n0 + wc * 64 + (lane & 15);
  int rb = m0 + wr * 128 + (lane >> 4) * 4;
#pragma unroll
  for (int mm = 0; mm < 8; ++mm)
#pragma unroll
    for (int n = 0; n < 4; ++n) {
      int c = cb + n * 16;
#pragma unroll
      for (int j = 0; j < 4; ++j) {
        int r = rb + mm * 16 + j;
        out[(size_t)r * DIN + c] =
            x[(size_t)r * DIN + c] * res_scale[c] + acc[mm][n][j] * layer_scale[c];
      }
    }
}

// ---------------- launch ----------------

extern "C" void kernel_launch(void* const* d_in, const int* in_sizes, int n_in,
                              void* d_out, int out_size, void* d_ws, size_t ws_size,
                              hipStream_t stream) {
  const float* x          = (const float*)d_in[0];
  const float* uv_w       = (const float*)d_in[1];
  const float* o_w        = (const float*)d_in[2];
  const float* gamma      = (const float*)d_in[3];
  const float* beta       = (const float*)d_in[4];
  const float* w          = (const float*)d_in[5];
  const float* g          = (const float*)d_in[6];
  const float* res_scale  = (const float*)d_in[7];
  const float* layer_scale= (const float*)d_in[8];
  float* out = (float*)d_out;

  char* ws = (char*)d_ws;
  // workspace layout (bytes), peak ~189 MB (< proven-good 197):
  u16* xn2    = (u16*)(ws + 0);            // 32 MB, dead after gemm_uv
  u16* q      = (u16*)(ws + 0);            // 8 MB (aliases dead xn2)
  u16* k      = (u16*)(ws + 8388608);      // 8 MB (aliases dead xn2)
  u16* scores = (u16*)(ws + 16777216);     // 32 MB (aliases dead xn2-upper + dead base)
  u16* base   = (u16*)(ws + 33554432);     // 8 MB, live gemm_uv -> qkbuild
  u16* u_io   = (u16*)(ws + 50331648);     // 64 MB: u, gated in place -> attn
  u16* vt     = (u16*)(ws + 117440512);    // 64 MB: v^T per batch
  u16* uvw_bf = (u16*)(ws + 184549376);    // 2.125 MB (+0.125 MB pad-read slack)
  u16* ow_bf  = (u16*)(ws + 186908672);    // 1 MB
  float* sin_t = (float*)(ws + 187957248); // 256 KB
  float* cos_t = (float*)(ws + 188219392); // 256 KB

  // prep
  k_f32_to_bf16<<<dim3((NUV * DIN / 4 + 255) / 256), 256, 0, stream>>>(uv_w, uvw_bf, NUV * DIN / 4);
  k_f32_to_bf16<<<dim3((DIN * EDIM / 4 + 255) / 256), 256, 0, stream>>>(o_w, ow_bf, DIN * EDIM / 4);
  k_rope_table<<<dim3(LSEQ * 64 / 256), 256, 0, stream>>>(sin_t, cos_t);
  k_normshift<<<dim3(NTOK), 256, 0, stream>>>(x, g, xn2);

  // uv projection + silu (256^2 per-slot-staged pipelined core)
  k_gemm_uv<<<dim3(1152), 512, 0, stream>>>(xn2, uvw_bf, u_io, vt, base);

  // q,k build (writes into dead xn2 region)
  k_qkbuild<<<dim3(NTOK * 64 / 256), 256, 0, stream>>>(base, gamma, beta, sin_t, cos_t, q, k);

  // scores + pv, chunked by 16 batches (scores = 32 MB, reused)
  for (int ch = 0; ch < NB / CHUNK; ++ch) {
    size_t tok0 = (size_t)ch * CHUNK * LSEQ;
    k_gemm_qk<<<dim3(256), 512, 0, stream>>>(q + tok0 * SDIM, k + tok0 * SDIM, w, scores);
    k_gemm_pv<<<dim3(256), 512, 0, stream>>>(scores, vt + tok0 * EDIM, u_io + tok0 * EDIM);
  }

  // final projection + residual (256^2 pipelined core)
  k_gemm_out<<<dim3(256), 512, 0, stream>>>(u_io, ow_bf, x, res_scale, layer_scale, out);
}